// Round 7
// baseline (153.100 us; speedup 1.0000x reference)
//
#include <hip/hip_runtime.h>
#include <hip/hip_bf16.h>
#include <stdint.h>

#define DEV __device__ __forceinline__

typedef __attribute__((ext_vector_type(8))) short short8;   // 8 bf16 (4 VGPRs)
typedef __attribute__((ext_vector_type(4))) float f32x4;    // MFMA acc

#define TWO_LOG2E 2.8853900817779268f   // 2*log2(e): exp(2x) == exp2(x*TWO_LOG2E)
#define MFMA16(a, b, c) __builtin_amdgcn_mfma_f32_16x16x32_bf16((a), (b), (c), 0, 0, 0)

// ---------------------------------------------------------------- helpers
DEV unsigned short f2bf(float f) {           // fp32 -> bf16, RNE
  uint32_t u = __float_as_uint(f);
  u += 0x7FFFu + ((u >> 16) & 1u);
  return (unsigned short)(u >> 16);
}

DEV uint2 pk4(float4 f) {                    // 4 fp32 -> 4 bf16 (packed cvt)
  union { __hip_bfloat162 h; unsigned u; } a, b;
  a.h = __float22bfloat162_rn(make_float2(f.x, f.y));
  b.h = __float22bfloat162_rn(make_float2(f.z, f.w));
  return make_uint2(a.u, b.u);
}

DEV short8 mk8(uint2 lo, uint2 hi) {
  union { short8 s; uint4 u; } t;
  t.u = make_uint4(lo.x, lo.y, hi.x, hi.y);
  return t.s;
}

DEV uint32_t rotl32(uint32_t x, int r) { return (x << r) | (x >> (32 - r)); }

// JAX Threefry-2x32 with key = (0, 42)  (jax.random.key(42))
DEV void threefry_0_42(uint32_t x0, uint32_t x1, uint32_t& o0, uint32_t& o1) {
  const uint32_t ks0 = 0u, ks1 = 42u, ks2 = 0x1BD11BDAu ^ 42u;
  x0 += ks0; x1 += ks1;
#define TFR(r) { x0 += x1; x1 = rotl32(x1, (r)); x1 ^= x0; }
  TFR(13) TFR(15) TFR(26) TFR(6)  x0 += ks1; x1 += ks2 + 1u;
  TFR(17) TFR(29) TFR(16) TFR(24) x0 += ks2; x1 += ks0 + 2u;
  TFR(13) TFR(15) TFR(26) TFR(6)  x0 += ks0; x1 += ks1 + 3u;
  TFR(17) TFR(29) TFR(16) TFR(24) x0 += ks1; x1 += ks2 + 4u;
  TFR(13) TFR(15) TFR(26) TFR(6)  x0 += ks2; x1 += ks0 + 5u;
#undef TFR
  o0 = x0; o1 = x1;
}

DEV float wredmax(float v) {
#pragma unroll
  for (int off = 32; off > 0; off >>= 1) v = fmaxf(v, __shfl_xor(v, off));
  return v;
}
DEV float wredsum(float v) {
#pragma unroll
  for (int off = 32; off > 0; off >>= 1) v += __shfl_xor(v, off);
  return v;
}

// ================================================================ prep: weight transposes only (144 blocks)
__global__ __launch_bounds__(256) void k_prep(const float* __restrict__ Wctx,
                                              const float* __restrict__ Wq,
                                              const float* __restrict__ Wout,
                                              unsigned short* __restrict__ WctxT,
                                              unsigned short* __restrict__ WqT,
                                              unsigned short* __restrict__ WoutT) {
  __shared__ float tile[64][65];
  const int b = blockIdx.x;
  const float* src; unsigned short* dst; int R, C, br, bc;
  if (b < 8)       { src = Wctx; dst = WctxT; R = 512;  C = 64;  br = b * 64;       bc = 0; }
  else if (b < 16) { src = Wq;   dst = WqT;   R = 512;  C = 64;  br = (b - 8) * 64; bc = 0; }
  else { int i = b - 16; src = Wout; dst = WoutT; R = 1024; C = 512; br = (i & 15) * 64; bc = (i >> 4) * 64; }
  const int tid = threadIdx.x;
  const int lr = tid >> 4, lc4 = (tid & 15) * 4;
#pragma unroll
  for (int i = 0; i < 4; ++i) {
    float4 vv = *(const float4*)(src + (long)(br + lr + i * 16) * C + bc + lc4);
    tile[lr + i * 16][lc4 + 0] = vv.x;
    tile[lr + i * 16][lc4 + 1] = vv.y;
    tile[lr + i * 16][lc4 + 2] = vv.z;
    tile[lr + i * 16][lc4 + 3] = vv.w;
  }
  __syncthreads();
#pragma unroll
  for (int i = 0; i < 4; ++i) {
    int crow = lr + i * 16;
    ushort4 o;
    o.x = f2bf(tile[lc4 + 0][crow]);
    o.y = f2bf(tile[lc4 + 1][crow]);
    o.z = f2bf(tile[lc4 + 2][crow]);
    o.w = f2bf(tile[lc4 + 3][crow]);
    *(ushort4*)(dst + (long)(bc + crow) * R + br + lc4) = o;
  }
}

// ================================================================ gemm1: uh(+mbT) / wq / P-pre  (528 blocks)
// t<256: uhT tile from mb fp32 (pk4-LDS); ALSO emits mbT bf16 [n][d][s] via Tr buffer.
// t 256..271: wq from input fp32. t>=272: P = input @ W_top + b.
__global__ __launch_bounds__(256) void k_gemm1(const float* __restrict__ mb,
                                               const float* __restrict__ input,
                                               const unsigned short* __restrict__ WctxT,
                                               const unsigned short* __restrict__ WqT,
                                               const unsigned short* __restrict__ WoutT,
                                               const float* __restrict__ bout,
                                               float* __restrict__ uhT,
                                               float* __restrict__ wqo,
                                               float* __restrict__ P,
                                               unsigned short* __restrict__ mbT) {
  __shared__ __align__(16) unsigned short As[64][32];
  __shared__ __align__(16) unsigned short Bs[64][32];
  __shared__ __align__(16) unsigned short Tr[32][72];   // 16B-aligned rows (144B stride)
  const int tid = threadIdx.x;
  const int t = blockIdx.x;
  const int srow = tid >> 2, kc = tid & 3;
  const int scol = ((kc ^ (srow & 3)) * 8);
  const int wave = tid >> 6, lane = tid & 63;
  const int q = lane >> 4, r = lane & 15;
  const int c0 = ((q ^ (r & 3)) * 8);

  if (t < 272) {
    const bool domb = (t < 256);
    const float* A; const unsigned short* BT; int mbase;
    if (domb) { A = mb;    BT = WctxT; mbase = t * 64; }
    else      { A = input; BT = WqT;   mbase = (t - 256) * 64; }
    const int n = mbase >> 10, s0 = mbase & 1023;      // for mbT (domb only)
    const int wm = (wave >> 1) * 32, wn = (wave & 1) * 32;
    const float* ap = A + (long)(mbase + srow) * 512 + kc * 8;
    const unsigned short* bp = BT + (long)srow * 512 + kc * 8;
    const int trow = tid >> 3, toff = (tid & 7) * 8;   // mbT writeout roles
    f32x4 acc[2][2];
#pragma unroll
    for (int i = 0; i < 2; ++i)
#pragma unroll
      for (int j = 0; j < 2; ++j) acc[i][j] = (f32x4){0.f, 0.f, 0.f, 0.f};
    float4 fa0 = *(const float4*)(ap);
    float4 fa1 = *(const float4*)(ap + 4);
    uint4 fb = *(const uint4*)(bp);
    for (int k0 = 0; k0 < 512; k0 += 32) {
      uint2 p0 = pk4(fa0), p1 = pk4(fa1);
      *(uint4*)&As[srow][scol] = make_uint4(p0.x, p0.y, p1.x, p1.y);
      *(uint4*)&Bs[srow][scol] = fb;
      if (domb) {                                      // transpose-scratch for mbT
        const int d0 = kc * 8;
        Tr[d0 + 0][srow] = (unsigned short)(p0.x & 0xFFFFu);
        Tr[d0 + 1][srow] = (unsigned short)(p0.x >> 16);
        Tr[d0 + 2][srow] = (unsigned short)(p0.y & 0xFFFFu);
        Tr[d0 + 3][srow] = (unsigned short)(p0.y >> 16);
        Tr[d0 + 4][srow] = (unsigned short)(p1.x & 0xFFFFu);
        Tr[d0 + 5][srow] = (unsigned short)(p1.x >> 16);
        Tr[d0 + 6][srow] = (unsigned short)(p1.y & 0xFFFFu);
        Tr[d0 + 7][srow] = (unsigned short)(p1.y >> 16);
      }
      __syncthreads();
      if (k0 + 32 < 512) {
        fa0 = *(const float4*)(ap + k0 + 32);
        fa1 = *(const float4*)(ap + k0 + 36);
        fb = *(const uint4*)(bp + k0 + 32);
      }
      short8 a0 = *(const short8*)&As[wm + r][c0];
      short8 a1 = *(const short8*)&As[wm + 16 + r][c0];
      short8 b0 = *(const short8*)&Bs[wn + r][c0];
      short8 b1 = *(const short8*)&Bs[wn + 16 + r][c0];
      acc[0][0] = MFMA16(a0, b0, acc[0][0]);
      acc[0][1] = MFMA16(a0, b1, acc[0][1]);
      acc[1][0] = MFMA16(a1, b0, acc[1][0]);
      acc[1][1] = MFMA16(a1, b1, acc[1][1]);
      if (domb) {                                      // coalesced mbT writeout (d-major)
        ushort4 w0 = *(const ushort4*)&Tr[trow][toff];
        ushort4 w1 = *(const ushort4*)&Tr[trow][toff + 4];
        unsigned short* dst = mbT + (long)n * 524288 + (long)(k0 + trow) * 1024 + s0 + toff;
        *(ushort4*)(dst) = w0;
        *(ushort4*)(dst + 4) = w1;
      }
      __syncthreads();
    }
#pragma unroll
    for (int i2 = 0; i2 < 2; ++i2)
#pragma unroll
      for (int j2 = 0; j2 < 2; ++j2) {
        int gcol = wn + j2 * 16 + r;
        int m = mbase + wm + i2 * 16 + q * 4;
        if (domb) {                                    // transposed: uhT[n][d][s]
          int nn = m >> 10, ss = m & 1023;
          float4 o;
          o.x = acc[i2][j2][0] * TWO_LOG2E;
          o.y = acc[i2][j2][1] * TWO_LOG2E;
          o.z = acc[i2][j2][2] * TWO_LOG2E;
          o.w = acc[i2][j2][3] * TWO_LOG2E;
          *(float4*)(uhT + (long)nn * 65536 + (long)gcol * 1024 + ss) = o;
        } else {
#pragma unroll
          for (int reg = 0; reg < 4; ++reg)
            wqo[(long)(m + reg) * 64 + gcol] = acc[i2][j2][reg] * TWO_LOG2E;
        }
      }
  } else {
    // ---- P = input @ W_top + b: 64x32 tile, K=512 ----
    const int tt = t - 272;
    const int mbase = (tt >> 4) * 64, nbase = (tt & 15) * 32;
    const int wm = (wave >> 1) * 32, wn = (wave & 1) * 16;
    const float* ap = input + (long)(mbase + srow) * 512 + kc * 8;
    const int brow = (tid & 127) >> 2;
    const unsigned short* bp = WoutT + (long)(nbase + brow) * 1024 + kc * 8;
    f32x4 acc[2];
    acc[0] = (f32x4){0.f, 0.f, 0.f, 0.f};
    acc[1] = (f32x4){0.f, 0.f, 0.f, 0.f};
    float4 fa0 = *(const float4*)(ap);
    float4 fa1 = *(const float4*)(ap + 4);
    uint4 fb;
    if (tid < 128) fb = *(const uint4*)(bp);
    for (int k0 = 0; k0 < 512; k0 += 32) {
      uint2 p0 = pk4(fa0), p1 = pk4(fa1);
      *(uint4*)&As[srow][scol] = make_uint4(p0.x, p0.y, p1.x, p1.y);
      if (tid < 128) *(uint4*)&Bs[brow][(kc ^ (brow & 3)) * 8] = fb;
      __syncthreads();
      int kn = k0 + 32;
      if (kn < 512) {
        fa0 = *(const float4*)(ap + kn);
        fa1 = *(const float4*)(ap + kn + 4);
        if (tid < 128) fb = *(const uint4*)(bp + kn);
      }
      short8 a0 = *(const short8*)&As[wm + r][c0];
      short8 a1 = *(const short8*)&As[wm + 16 + r][c0];
      short8 b0 = *(const short8*)&Bs[wn + r][c0];
      acc[0] = MFMA16(a0, b0, acc[0]);
      acc[1] = MFMA16(a1, b0, acc[1]);
      __syncthreads();
    }
#pragma unroll
    for (int i2 = 0; i2 < 2; ++i2) {
      int gcol = nbase + wn + r;
      float bb = bout[gcol];
#pragma unroll
      for (int reg = 0; reg < 4; ++reg) {
        int grow = mbase + wm + i2 * 16 + q * 4 + reg;
        P[(long)grow * 512 + gcol] = acc[i2][reg] + bb;
      }
    }
  }
}

// ================================================================ scores + softmax + gumbel (bf16 out), XCD-pinned
DEV void softmax_gumbel_write(float* lsc, int nt, int tid, float* red,
                              unsigned short* alpha_bf, unsigned short* yal_bf) {
  const int wv = tid >> 6, ln = tid & 63;
  float m = fmaxf(fmaxf(lsc[0], lsc[1]), fmaxf(lsc[2], lsc[3]));
  m = wredmax(m);
  if (ln == 0) red[wv] = m;
  __syncthreads();
  m = fmaxf(fmaxf(red[0], red[1]), fmaxf(red[2], red[3]));
  __syncthreads();
  float ss = 0.f;
#pragma unroll
  for (int i = 0; i < 4; ++i) ss += __expf(lsc[i] - m);
  ss = wredsum(ss);
  if (ln == 0) red[wv] = ss;
  __syncthreads();
  ss = red[0] + red[1] + red[2] + red[3];
  const float logl = __logf(ss);
  __syncthreads();

  const uint32_t jbase = (uint32_t)nt * 1024u + (uint32_t)tid * 4u;
  float ys[4];
  float4 av;
#pragma unroll
  for (int i = 0; i < 4; ++i) {
    float la = lsc[i] - m - logl;
    ((float*)&av)[i] = __expf(la);
    uint32_t o0, o1;
    threefry_0_42(0u, jbase + i, o0, o1);
    uint32_t bits = o0 ^ o1;
    float u = __uint_as_float((bits >> 9) | 0x3f800000u) - 1.0f;
    float g = -__logf(-__logf(u + 1e-20f) + 1e-20f);
    ys[i] = (la + g) * 2.0f;                           // /TEMPERATURE (0.5)
  }
  {
    uint2 pa = pk4(av);
    *(uint2*)(alpha_bf + (long)nt * 1024 + tid * 4) = pa;
  }
  float m2 = fmaxf(fmaxf(ys[0], ys[1]), fmaxf(ys[2], ys[3]));
  m2 = wredmax(m2);
  if (ln == 0) red[wv] = m2;
  __syncthreads();
  m2 = fmaxf(fmaxf(red[0], red[1]), fmaxf(red[2], red[3]));
  __syncthreads();
  float s2 = 0.f;
  float4 ye;
#pragma unroll
  for (int i = 0; i < 4; ++i) { ((float*)&ye)[i] = __expf(ys[i] - m2); s2 += ((float*)&ye)[i]; }
  s2 = wredsum(s2);
  if (ln == 0) red[wv] = s2;
  __syncthreads();
  s2 = red[0] + red[1] + red[2] + red[3];
  const float rinv = __fdividef(1.f, s2);
  ye.x *= rinv; ye.y *= rinv; ye.z *= rinv; ye.w *= rinv;
  {
    uint2 py = pk4(ye);
    *(uint2*)(yal_bf + (long)nt * 1024 + tid * 4) = py;
  }
  __syncthreads();
}

__global__ __launch_bounds__(256) void k_scores(const float* __restrict__ uhT,
                                                const float* __restrict__ wqo,
                                                const float* __restrict__ vvec,
                                                unsigned short* __restrict__ alpha_bf,
                                                unsigned short* __restrict__ yal_bf) {
  __shared__ __align__(16) float smf[196];
  float* wvs0 = smf;
  float* wvs1 = smf + 64;
  float* vvs  = smf + 128;
  float* red  = smf + 192;
  const int tid = threadIdx.x;
  // XCD-bijective swizzle: XCD x handles n in {x, x+8} -> uhT[n] L2-resident
  const int bid = blockIdx.x;
  const int nt0 = ((bid & 7) << 6) | (bid >> 3);
  const int nt1 = nt0 + 512;
  const int n0 = nt0 >> 6, n1 = nt1 >> 6;
  if (tid < 64) {
    wvs0[tid] = wqo[nt0 * 64 + tid];
    wvs1[tid] = wqo[nt1 * 64 + tid];
    vvs[tid]  = vvec[tid];
  }
  __syncthreads();
  float sumv = 0.f;
#pragma unroll
  for (int d = 0; d < 64; d += 4) {
    float4 vv = *(const float4*)&vvs[d];
    sumv += vv.x + vv.y + vv.z + vv.w;
  }
  const float* un0 = uhT + (long)n0 * 65536 + tid * 4;
  const float* un1 = uhT + (long)n1 * 65536 + tid * 4;
  float4 r0 = make_float4(0.f, 0.f, 0.f, 0.f);
  float4 r1 = make_float4(0.f, 0.f, 0.f, 0.f);
  for (int db = 0; db < 64; db += 4) {
    float4 ua[4], ub[4];
#pragma unroll
    for (int j = 0; j < 4; ++j) {
      ua[j] = *(const float4*)(un0 + (long)(db + j) * 1024);
      ub[j] = *(const float4*)(un1 + (long)(db + j) * 1024);
    }
#pragma unroll
    for (int j = 0; j < 4; ++j) {
      float w0 = wvs0[db + j], w1 = wvs1[db + j], vvj = vvs[db + j];
      r0.x = fmaf(vvj, __builtin_amdgcn_rcpf(1.f + __builtin_amdgcn_exp2f(ua[j].x + w0)), r0.x);
      r0.y = fmaf(vvj, __builtin_amdgcn_rcpf(1.f + __builtin_amdgcn_exp2f(ua[j].y + w0)), r0.y);
      r0.z = fmaf(vvj, __builtin_amdgcn_rcpf(1.f + __builtin_amdgcn_exp2f(ua[j].z + w0)), r0.z);
      r0.w = fmaf(vvj, __builtin_amdgcn_rcpf(1.f + __builtin_amdgcn_exp2f(ua[j].w + w0)), r0.w);
      r1.x = fmaf(vvj, __builtin_amdgcn_rcpf(1.f + __builtin_amdgcn_exp2f(ub[j].x + w1)), r1.x);
      r1.y = fmaf(vvj, __builtin_amdgcn_rcpf(1.f + __builtin_amdgcn_exp2f(ub[j].y + w1)), r1.y);
      r1.z = fmaf(vvj, __builtin_amdgcn_rcpf(1.f + __builtin_amdgcn_exp2f(ub[j].z + w1)), r1.z);
      r1.w = fmaf(vvj, __builtin_amdgcn_rcpf(1.f + __builtin_amdgcn_exp2f(ub[j].w + w1)), r1.w);
    }
  }
  float lsc0[4], lsc1[4];
  lsc0[0] = fmaf(-2.f, r0.x, sumv); lsc0[1] = fmaf(-2.f, r0.y, sumv);
  lsc0[2] = fmaf(-2.f, r0.z, sumv); lsc0[3] = fmaf(-2.f, r0.w, sumv);
  lsc1[0] = fmaf(-2.f, r1.x, sumv); lsc1[1] = fmaf(-2.f, r1.y, sumv);
  lsc1[2] = fmaf(-2.f, r1.z, sumv); lsc1[3] = fmaf(-2.f, r1.w, sumv);
  softmax_gumbel_write(lsc0, nt0, tid, red, alpha_bf, yal_bf);
  softmax_gumbel_write(lsc1, nt1, tid, red, alpha_bf, yal_bf);
}

// ================================================================ ctx: LDS A staging (bf16 direct) + reg B from mbT
__global__ __launch_bounds__(256) void k_ctx(const unsigned short* __restrict__ alpha_bf,
                                             const unsigned short* __restrict__ yal_bf,
                                             const unsigned short* __restrict__ mbT,
                                             unsigned short* __restrict__ ctxb) {
  __shared__ __align__(16) unsigned short As[64][32];
  const int tid = threadIdx.x;
  const int x = blockIdx.x;                 // n = x&15 -> same-n blocks share an XCD
  const int n = x & 15, dbase = ((x >> 4) & 15) * 32, vt = x >> 8;
  const int srow = tid >> 2, kc = tid & 3;
  const int scol = ((kc ^ (srow & 3)) * 8);
  const int wave = tid >> 6, lane = tid & 63;
  const int wm = (wave >> 1) * 32, wn = (wave & 1) * 16;
  const int q = lane >> 4, r = lane & 15;
  const int c0 = ((q ^ (r & 3)) * 8);
  const unsigned short* Ab = (vt ? yal_bf : alpha_bf) + (long)n * 65536 + (long)srow * 1024 + kc * 8;
  const unsigned short* Bp = mbT + (long)n * 524288 + (long)(dbase + wn + r) * 1024 + q * 8;
  f32x4 acc[2];
  acc[0] = (f32x4){0.f, 0.f, 0.f, 0.f};
  acc[1] = (f32x4){0.f, 0.f, 0.f, 0.f};
  uint4 fa  = *(const uint4*)(Ab);
  uint4 fb0 = *(const uint4*)(Bp);          // k-step 0
  uint4 fb1 = *(const uint4*)(Bp + 32);     // k-step 1 (2-deep prefetch)
  for (int k0 = 0; k0 < 1024; k0 += 32) {
    *(uint4*)&As[srow][scol] = fa;
    __syncthreads();
    union { uint4 u; short8 s; } bu; bu.u = fb0;
    if (k0 + 32 < 1024) fa = *(const uint4*)(Ab + k0 + 32);
    fb0 = fb1;
    if (k0 + 64 < 1024) fb1 = *(const uint4*)(Bp + k0 + 64);
    short8 a0 = *(const short8*)&As[wm + r][c0];
    short8 a1 = *(const short8*)&As[wm + 16 + r][c0];
    acc[0] = MFMA16(a0, bu.s, acc[0]);
    acc[1] = MFMA16(a1, bu.s, acc[1]);
    __syncthreads();
  }
#pragma unroll
  for (int i2 = 0; i2 < 2; ++i2) {
    int gcol = dbase + wn + r;
#pragma unroll
    for (int reg = 0; reg < 4; ++reg) {
      long grow = (long)vt * 1024 + n * 64 + wm + i2 * 16 + q * 4 + reg;
      ctxb[grow * 512 + gcol] = f2bf(acc[i2][reg]);
    }
  }
}

// ================================================================ out = tanh(P + ctx @ W_bot)
__global__ __launch_bounds__(256) void k_out(const unsigned short* __restrict__ ctxb,
                                             const unsigned short* __restrict__ WoutT,
                                             const float* __restrict__ P,
                                             float* __restrict__ out) {
  __shared__ __align__(16) unsigned short As[64][32];
  __shared__ __align__(16) unsigned short Bs[32][32];
  const int tid = threadIdx.x;
  const int mbase = (blockIdx.x >> 4) * 64, nbase = (blockIdx.x & 15) * 32;
  const int srow = tid >> 2, kc = tid & 3;
  const int scol = ((kc ^ (srow & 3)) * 8);
  const int wave = tid >> 6, lane = tid & 63;
  const int wm = (wave >> 1) * 32, wn = (wave & 1) * 16;
  const int q = lane >> 4, r = lane & 15;
  const int c0 = ((q ^ (r & 3)) * 8);
  const unsigned short* ap = ctxb + (long)(mbase + srow) * 512 + kc * 8;
  const int brow = (tid & 127) >> 2;
  const unsigned short* bp = WoutT + (long)(nbase + brow) * 1024 + 512 + kc * 8;
  f32x4 acc[2];
#pragma unroll
  for (int i2 = 0; i2 < 2; ++i2) {
    int pcol = nbase + wn + r;
#pragma unroll
    for (int reg = 0; reg < 4; ++reg) {
      int prow = (mbase + wm + i2 * 16 + q * 4 + reg) & 1023;
      acc[i2][reg] = P[(long)prow * 512 + pcol];
    }
  }
  uint4 fa = *(const uint4*)(ap);
  uint4 fb;
  if (tid < 128) fb = *(const uint4*)(bp);
  for (int k0 = 0; k0 < 512; k0 += 32) {
    *(uint4*)&As[srow][scol] = fa;
    if (tid < 128) *(uint4*)&Bs[brow][(kc ^ (brow & 3)) * 8] = fb;
    __syncthreads();
    int kn = k0 + 32;
    if (kn < 512) {
      fa = *(const uint4*)(ap + kn);
      if (tid < 128) fb = *(const uint4*)(bp + kn);
    }
    short8 a0 = *(const short8*)&As[wm + r][c0];
    short8 a1 = *(const short8*)&As[wm + 16 + r][c0];
    short8 b0 = *(const short8*)&Bs[wn + r][c0];
    acc[0] = MFMA16(a0, b0, acc[0]);
    acc[1] = MFMA16(a1, b0, acc[1]);
    __syncthreads();
  }
#pragma unroll
  for (int i2 = 0; i2 < 2; ++i2) {
    int gcol = nbase + wn + r;
#pragma unroll
    for (int reg = 0; reg < 4; ++reg) {
      int grow = mbase + wm + i2 * 16 + q * 4 + reg;
      float z = acc[i2][reg];
      float rc = __builtin_amdgcn_rcpf(1.f + __builtin_amdgcn_exp2f(z * TWO_LOG2E));
      out[(long)grow * 512 + gcol] = fmaf(-2.f, rc, 1.f);
    }
  }
}

// ================================================================ launch
// ws layout (float units):
//   uhT      [0       , 1048576)   fp32 [16][64][1024] TRANSPOSED, prescaled
//   wqo      [1048576 , 1114112)   fp32 [1024][64], prescaled
//   alpha_bf [1114112 , 1638400)   bf16 [16][64][1024]
//   yal_bf   [1638400 , 2162688)   bf16 [16][64][1024]
//   WctxT    [2162688 , 2179072)   bf16 [64][512]
//   WqT      [2179072 , 2195456)   bf16 [64][512]
//   WoutT    [2195456 , 2457600)   bf16 [512][1024]
//   ctxb     [2457600 , 2981888)   bf16 [2048][512]
//   P        [2981888 , 3506176)   fp32 [1024][512]
//   mbT      [3506176 , 7700480)   bf16 [16][512][1024]  (written by k_gemm1 uh blocks)
extern "C" void kernel_launch(void* const* d_in, const int* in_sizes, int n_in,
                              void* d_out, int out_size, void* d_ws, size_t ws_size,
                              hipStream_t stream) {
  const float* input = (const float*)d_in[0];   // [16,64,512]
  const float* mb    = (const float*)d_in[1];   // [16,1024,512]
  const float* W_q   = (const float*)d_in[2];   // [512,64]
  const float* W_ctx = (const float*)d_in[3];   // [512,64]
  const float* v     = (const float*)d_in[4];   // [64]
  const float* W_out = (const float*)d_in[5];   // [1024,512]
  const float* b_out = (const float*)d_in[6];   // [512]
  float* out = (float*)d_out;                   // [2,16,64,512]
  float* ws = (float*)d_ws;

  float* uhT = ws;
  float* wqo = ws + 1048576;
  unsigned short* alpha_bf = (unsigned short*)(ws + 1114112);
  unsigned short* yal_bf   = (unsigned short*)(ws + 1638400);
  unsigned short* WctxT = (unsigned short*)(ws + 2162688);
  unsigned short* WqT   = (unsigned short*)(ws + 2179072);
  unsigned short* WoutT = (unsigned short*)(ws + 2195456);
  unsigned short* ctxb  = (unsigned short*)(ws + 2457600);
  float* P = ws + 2981888;
  unsigned short* mbT = (unsigned short*)(ws + 3506176);

  k_prep<<<144, 256, 0, stream>>>(W_ctx, W_q, W_out, WctxT, WqT, WoutT);
  k_gemm1<<<528, 256, 0, stream>>>(mb, input, WctxT, WqT, WoutT, b_out, uhT, wqo, P, mbT);
  k_scores<<<512, 256, 0, stream>>>(uhT, wqo, v, alpha_bf, yal_bf);
  k_ctx<<<512, 256, 0, stream>>>(alpha_bf, yal_bf, mbT, ctxb);
  k_out<<<512, 256, 0, stream>>>(ctxb, WoutT, P, out);
}

// Round 8
// 151.564 us; speedup vs baseline: 1.0101x; 1.0101x over previous
//
#include <hip/hip_runtime.h>
#include <hip/hip_bf16.h>
#include <stdint.h>

#define DEV __device__ __forceinline__

typedef __attribute__((ext_vector_type(8))) short short8;   // 8 bf16 (4 VGPRs)
typedef __attribute__((ext_vector_type(4))) float f32x4;    // MFMA acc

#define TWO_LOG2E 2.8853900817779268f   // 2*log2(e): exp(2x) == exp2(x*TWO_LOG2E)
#define MFMA16(a, b, c) __builtin_amdgcn_mfma_f32_16x16x32_bf16((a), (b), (c), 0, 0, 0)

// ---------------------------------------------------------------- helpers
DEV unsigned short f2bf(float f) {           // fp32 -> bf16, RNE
  uint32_t u = __float_as_uint(f);
  u += 0x7FFFu + ((u >> 16) & 1u);
  return (unsigned short)(u >> 16);
}

DEV uint2 pk4(float4 f) {                    // 4 fp32 -> 4 bf16 (packed cvt)
  union { __hip_bfloat162 h; unsigned u; } a, b;
  a.h = __float22bfloat162_rn(make_float2(f.x, f.y));
  b.h = __float22bfloat162_rn(make_float2(f.z, f.w));
  return make_uint2(a.u, b.u);
}

DEV uint32_t rotl32(uint32_t x, int r) { return (x << r) | (x >> (32 - r)); }

// JAX Threefry-2x32 with key = (0, 42)  (jax.random.key(42))
DEV void threefry_0_42(uint32_t x0, uint32_t x1, uint32_t& o0, uint32_t& o1) {
  const uint32_t ks0 = 0u, ks1 = 42u, ks2 = 0x1BD11BDAu ^ 42u;
  x0 += ks0; x1 += ks1;
#define TFR(r) { x0 += x1; x1 = rotl32(x1, (r)); x1 ^= x0; }
  TFR(13) TFR(15) TFR(26) TFR(6)  x0 += ks1; x1 += ks2 + 1u;
  TFR(17) TFR(29) TFR(16) TFR(24) x0 += ks2; x1 += ks0 + 2u;
  TFR(13) TFR(15) TFR(26) TFR(6)  x0 += ks0; x1 += ks1 + 3u;
  TFR(17) TFR(29) TFR(16) TFR(24) x0 += ks1; x1 += ks2 + 4u;
  TFR(13) TFR(15) TFR(26) TFR(6)  x0 += ks2; x1 += ks0 + 5u;
#undef TFR
  o0 = x0; o1 = x1;
}

DEV float wredmax(float v) {
#pragma unroll
  for (int off = 32; off > 0; off >>= 1) v = fmaxf(v, __shfl_xor(v, off));
  return v;
}
DEV float wredsum(float v) {
#pragma unroll
  for (int off = 32; off > 0; off >>= 1) v += __shfl_xor(v, off);
  return v;
}

// ================================================================ prep: weight transposes only (144 blocks)
__global__ __launch_bounds__(256) void k_prep(const float* __restrict__ Wctx,
                                              const float* __restrict__ Wq,
                                              const float* __restrict__ Wout,
                                              unsigned short* __restrict__ WctxT,
                                              unsigned short* __restrict__ WqT,
                                              unsigned short* __restrict__ WoutT) {
  __shared__ float tile[64][65];
  const int b = blockIdx.x;
  const float* src; unsigned short* dst; int R, C, br, bc;
  if (b < 8)       { src = Wctx; dst = WctxT; R = 512;  C = 64;  br = b * 64;       bc = 0; }
  else if (b < 16) { src = Wq;   dst = WqT;   R = 512;  C = 64;  br = (b - 8) * 64; bc = 0; }
  else { int i = b - 16; src = Wout; dst = WoutT; R = 1024; C = 512; br = (i & 15) * 64; bc = (i >> 4) * 64; }
  const int tid = threadIdx.x;
  const int lr = tid >> 4, lc4 = (tid & 15) * 4;
#pragma unroll
  for (int i = 0; i < 4; ++i) {
    float4 vv = *(const float4*)(src + (long)(br + lr + i * 16) * C + bc + lc4);
    tile[lr + i * 16][lc4 + 0] = vv.x;
    tile[lr + i * 16][lc4 + 1] = vv.y;
    tile[lr + i * 16][lc4 + 2] = vv.z;
    tile[lr + i * 16][lc4 + 3] = vv.w;
  }
  __syncthreads();
#pragma unroll
  for (int i = 0; i < 4; ++i) {
    int crow = lr + i * 16;
    ushort4 o;
    o.x = f2bf(tile[lc4 + 0][crow]);
    o.y = f2bf(tile[lc4 + 1][crow]);
    o.z = f2bf(tile[lc4 + 2][crow]);
    o.w = f2bf(tile[lc4 + 3][crow]);
    *(ushort4*)(dst + (long)(bc + crow) * R + br + lc4) = o;
  }
}

// ================================================================ gemm1 (1056 blocks, 32-row tiles -> 4+/CU)
// t<512: uh 32-s tile (emits uhT transposed + mbT bf16 slice)
// t in [512,544): wq 32-row tile
// t>=544: P = input @ W_top + b, 32x32 tile
__global__ __launch_bounds__(256) void k_gemm1(const float* __restrict__ mb,
                                               const float* __restrict__ input,
                                               const unsigned short* __restrict__ WctxT,
                                               const unsigned short* __restrict__ WqT,
                                               const unsigned short* __restrict__ WoutT,
                                               const float* __restrict__ bout,
                                               float* __restrict__ uhT,
                                               float* __restrict__ wqo,
                                               float* __restrict__ P,
                                               unsigned short* __restrict__ mbT) {
  __shared__ __align__(16) unsigned short As[32][32];   // 2 KB
  __shared__ __align__(16) unsigned short Bs[64][32];   // 4 KB (P path uses first 32 rows)
  __shared__ __align__(16) unsigned short Tr[32][33];   // mbT transpose scratch
  const int tid = threadIdx.x;
  const int t = blockIdx.x;
  const int wave = tid >> 6, lane = tid & 63;
  const int q = lane >> 4, r = lane & 15;
  const int c0 = ((q ^ (r & 3)) * 8);

  if (t < 544) {
    // ---- uh (t<512) / wq: M=32, N=64, K=512 ----
    const bool domb = (t < 512);
    const float* A; const unsigned short* BT; int mbase;
    if (domb) { A = mb;    BT = WctxT; mbase = t * 32; }
    else      { A = input; BT = WqT;   mbase = (t - 512) * 32; }
    const int n = mbase >> 10, s0 = mbase & 1023;       // for mbT (domb)
    const int wi = wave >> 1, wn = (wave & 1) * 32;
    const int arow = (tid & 127) >> 2, akc = tid & 3;
    const int ascol = ((akc ^ (arow & 3)) * 8);
    const float* ap = A + (long)(mbase + arow) * 512 + akc * 8;
    const int brow = tid >> 2, bkc = tid & 3;
    const int bscol = ((bkc ^ (brow & 3)) * 8);
    const unsigned short* bp = BT + (long)brow * 512 + bkc * 8;
    const int trow = tid >> 3, toff = (tid & 7) * 4;
    f32x4 acc[2];
    acc[0] = (f32x4){0.f, 0.f, 0.f, 0.f};
    acc[1] = (f32x4){0.f, 0.f, 0.f, 0.f};
    float4 fa0, fa1;
    if (tid < 128) { fa0 = *(const float4*)(ap); fa1 = *(const float4*)(ap + 4); }
    uint4 fb = *(const uint4*)(bp);
    for (int k0 = 0; k0 < 512; k0 += 32) {
      if (tid < 128) {
        uint2 p0 = pk4(fa0), p1 = pk4(fa1);
        *(uint4*)&As[arow][ascol] = make_uint4(p0.x, p0.y, p1.x, p1.y);
        if (domb) {                                      // Tr[d][s] scratch (d = akc*8+j)
          const int d0 = akc * 8;
          Tr[d0 + 0][arow] = (unsigned short)(p0.x & 0xFFFFu);
          Tr[d0 + 1][arow] = (unsigned short)(p0.x >> 16);
          Tr[d0 + 2][arow] = (unsigned short)(p0.y & 0xFFFFu);
          Tr[d0 + 3][arow] = (unsigned short)(p0.y >> 16);
          Tr[d0 + 4][arow] = (unsigned short)(p1.x & 0xFFFFu);
          Tr[d0 + 5][arow] = (unsigned short)(p1.x >> 16);
          Tr[d0 + 6][arow] = (unsigned short)(p1.y & 0xFFFFu);
          Tr[d0 + 7][arow] = (unsigned short)(p1.y >> 16);
        }
      }
      *(uint4*)&Bs[brow][bscol] = fb;
      __syncthreads();
      if (k0 + 32 < 512) {
        if (tid < 128) {
          fa0 = *(const float4*)(ap + k0 + 32);
          fa1 = *(const float4*)(ap + k0 + 36);
        }
        fb = *(const uint4*)(bp + k0 + 32);
      }
      short8 a0 = *(const short8*)&As[wi * 16 + r][c0];
      short8 b0 = *(const short8*)&Bs[wn + r][c0];
      short8 b1 = *(const short8*)&Bs[wn + 16 + r][c0];
      acc[0] = MFMA16(a0, b0, acc[0]);
      acc[1] = MFMA16(a0, b1, acc[1]);
      if (domb) {                                        // coalesced mbT writeout (d-major)
        ushort4 w0 = *(const ushort4*)&Tr[trow][toff];
        *(ushort4*)(mbT + (long)n * 524288 + (long)(k0 + trow) * 1024 + s0 + toff) = w0;
      }
      __syncthreads();
    }
#pragma unroll
    for (int j2 = 0; j2 < 2; ++j2) {
      int gcol = wn + j2 * 16 + r;
      int m = mbase + wi * 16 + q * 4;
      if (domb) {                                        // transposed: uhT[n][d][s]
        float4 o;
        o.x = acc[j2][0] * TWO_LOG2E;
        o.y = acc[j2][1] * TWO_LOG2E;
        o.z = acc[j2][2] * TWO_LOG2E;
        o.w = acc[j2][3] * TWO_LOG2E;
        *(float4*)(uhT + (long)n * 65536 + (long)gcol * 1024 + (m & 1023)) = o;
      } else {
#pragma unroll
        for (int reg = 0; reg < 4; ++reg)
          wqo[(long)(m + reg) * 64 + gcol] = acc[j2][reg] * TWO_LOG2E;
      }
    }
  } else {
    // ---- P = input @ W_top + b: 32x32 tile, K=512 ----
    const int tt = t - 544;
    const int mbase = (tt >> 4) * 32, nbase = (tt & 15) * 32;
    const int wi = wave >> 1, wj = wave & 1;
    const int arow = (tid & 127) >> 2, akc = tid & 3;
    const int ascol = ((akc ^ (arow & 3)) * 8);
    const float* ap = input + (long)(mbase + arow) * 512 + akc * 8;
    const unsigned short* bp = WoutT + (long)(nbase + arow) * 1024 + akc * 8;
    f32x4 acc = (f32x4){0.f, 0.f, 0.f, 0.f};
    float4 fa0, fa1; uint4 fb;
    if (tid < 128) { fa0 = *(const float4*)(ap); fa1 = *(const float4*)(ap + 4); }
    else           { fb = *(const uint4*)(bp); }
    for (int k0 = 0; k0 < 512; k0 += 32) {
      if (tid < 128) {
        uint2 p0 = pk4(fa0), p1 = pk4(fa1);
        *(uint4*)&As[arow][ascol] = make_uint4(p0.x, p0.y, p1.x, p1.y);
      } else {
        *(uint4*)&Bs[arow][ascol] = fb;
      }
      __syncthreads();
      int kn = k0 + 32;
      if (kn < 512) {
        if (tid < 128) {
          fa0 = *(const float4*)(ap + kn);
          fa1 = *(const float4*)(ap + kn + 4);
        } else {
          fb = *(const uint4*)(bp + kn);
        }
      }
      short8 a0 = *(const short8*)&As[wi * 16 + r][c0];
      short8 b0 = *(const short8*)&Bs[wj * 16 + r][c0];
      acc = MFMA16(a0, b0, acc);
      __syncthreads();
    }
    int gcol = nbase + wj * 16 + r;
    float bb = bout[gcol];
#pragma unroll
    for (int reg = 0; reg < 4; ++reg) {
      int grow = mbase + wi * 16 + q * 4 + reg;
      P[(long)grow * 512 + gcol] = acc[reg] + bb;
    }
  }
}

// ================================================================ scores + softmax + gumbel (1024 blocks, 1 nt each)
DEV void softmax_gumbel_write(float* lsc, int nt, int tid, float* red,
                              unsigned short* alpha_bf, unsigned short* yal_bf) {
  const int wv = tid >> 6, ln = tid & 63;
  float m = fmaxf(fmaxf(lsc[0], lsc[1]), fmaxf(lsc[2], lsc[3]));
  m = wredmax(m);
  if (ln == 0) red[wv] = m;
  __syncthreads();
  m = fmaxf(fmaxf(red[0], red[1]), fmaxf(red[2], red[3]));
  __syncthreads();
  float ss = 0.f;
#pragma unroll
  for (int i = 0; i < 4; ++i) ss += __expf(lsc[i] - m);
  ss = wredsum(ss);
  if (ln == 0) red[wv] = ss;
  __syncthreads();
  ss = red[0] + red[1] + red[2] + red[3];
  const float logl = __logf(ss);
  __syncthreads();

  const uint32_t jbase = (uint32_t)nt * 1024u + (uint32_t)tid * 4u;
  float ys[4];
  float4 av;
#pragma unroll
  for (int i = 0; i < 4; ++i) {
    float la = lsc[i] - m - logl;
    ((float*)&av)[i] = __expf(la);
    uint32_t o0, o1;
    threefry_0_42(0u, jbase + i, o0, o1);
    uint32_t bits = o0 ^ o1;
    float u = __uint_as_float((bits >> 9) | 0x3f800000u) - 1.0f;
    float g = -__logf(-__logf(u + 1e-20f) + 1e-20f);
    ys[i] = (la + g) * 2.0f;                           // /TEMPERATURE (0.5)
  }
  {
    uint2 pa = pk4(av);
    *(uint2*)(alpha_bf + (long)nt * 1024 + tid * 4) = pa;
  }
  float m2 = fmaxf(fmaxf(ys[0], ys[1]), fmaxf(ys[2], ys[3]));
  m2 = wredmax(m2);
  if (ln == 0) red[wv] = m2;
  __syncthreads();
  m2 = fmaxf(fmaxf(red[0], red[1]), fmaxf(red[2], red[3]));
  __syncthreads();
  float s2 = 0.f;
  float4 ye;
#pragma unroll
  for (int i = 0; i < 4; ++i) { ((float*)&ye)[i] = __expf(ys[i] - m2); s2 += ((float*)&ye)[i]; }
  s2 = wredsum(s2);
  if (ln == 0) red[wv] = s2;
  __syncthreads();
  s2 = red[0] + red[1] + red[2] + red[3];
  const float rinv = __fdividef(1.f, s2);
  ye.x *= rinv; ye.y *= rinv; ye.z *= rinv; ye.w *= rinv;
  {
    uint2 py = pk4(ye);
    *(uint2*)(yal_bf + (long)nt * 1024 + tid * 4) = py;
  }
}

__global__ __launch_bounds__(256) void k_scores(const float* __restrict__ uhT,
                                                const float* __restrict__ wqo,
                                                const float* __restrict__ vvec,
                                                unsigned short* __restrict__ alpha_bf,
                                                unsigned short* __restrict__ yal_bf) {
  __shared__ __align__(16) float smf[132];
  float* wvs = smf;
  float* vvs = smf + 64;
  float* red = smf + 128;
  const int tid = threadIdx.x;
  // XCD-bijective swizzle: XCD x handles n in {2x, 2x+1} -> uhT[n] L2-resident
  const int bid = blockIdx.x;
  const int nt = ((bid & 7) << 7) | (bid >> 3);
  const int n = nt >> 6;
  if (tid < 64) {
    wvs[tid] = wqo[nt * 64 + tid];
    vvs[tid] = vvec[tid];
  }
  __syncthreads();
  float sumv = 0.f;
#pragma unroll
  for (int d = 0; d < 64; d += 4) {
    float4 vv = *(const float4*)&vvs[d];
    sumv += vv.x + vv.y + vv.z + vv.w;
  }
  const float* un = uhT + (long)n * 65536 + tid * 4;
  float4 racc = make_float4(0.f, 0.f, 0.f, 0.f);
  for (int db = 0; db < 64; db += 8) {
    float4 ub[8];
#pragma unroll
    for (int j = 0; j < 8; ++j) ub[j] = *(const float4*)(un + (long)(db + j) * 1024);
#pragma unroll
    for (int j = 0; j < 8; ++j) {
      float w = wvs[db + j], vvj = vvs[db + j];
      racc.x = fmaf(vvj, __builtin_amdgcn_rcpf(1.f + __builtin_amdgcn_exp2f(ub[j].x + w)), racc.x);
      racc.y = fmaf(vvj, __builtin_amdgcn_rcpf(1.f + __builtin_amdgcn_exp2f(ub[j].y + w)), racc.y);
      racc.z = fmaf(vvj, __builtin_amdgcn_rcpf(1.f + __builtin_amdgcn_exp2f(ub[j].z + w)), racc.z);
      racc.w = fmaf(vvj, __builtin_amdgcn_rcpf(1.f + __builtin_amdgcn_exp2f(ub[j].w + w)), racc.w);
    }
  }
  float lsc[4];
  lsc[0] = fmaf(-2.f, racc.x, sumv);
  lsc[1] = fmaf(-2.f, racc.y, sumv);
  lsc[2] = fmaf(-2.f, racc.z, sumv);
  lsc[3] = fmaf(-2.f, racc.w, sumv);
  softmax_gumbel_write(lsc, nt, tid, red, alpha_bf, yal_bf);
}

// ================================================================ ctx (1024 blocks, 32x32): LDS A + reg B from mbT
__global__ __launch_bounds__(256) void k_ctx(const unsigned short* __restrict__ alpha_bf,
                                             const unsigned short* __restrict__ yal_bf,
                                             const unsigned short* __restrict__ mbT,
                                             unsigned short* __restrict__ ctxb) {
  __shared__ __align__(16) unsigned short As[32][32];
  const int tid = threadIdx.x;
  const int x = blockIdx.x;                 // n = x&15 -> same-n blocks share an XCD
  const int n = x & 15, dbase = ((x >> 4) & 15) * 32, mt = (x >> 8) & 1, vt = x >> 9;
  const int wave = tid >> 6, lane = tid & 63;
  const int wi = wave >> 1, wj = wave & 1;
  const int q = lane >> 4, r = lane & 15;
  const int c0 = ((q ^ (r & 3)) * 8);
  const int arow = (tid & 127) >> 2, akc = tid & 3;
  const int ascol = ((akc ^ (arow & 3)) * 8);
  const unsigned short* ap = (vt ? yal_bf : alpha_bf) + (long)n * 65536
                             + (long)(mt * 32 + arow) * 1024 + akc * 8;
  const unsigned short* Bp = mbT + (long)n * 524288 + (long)(dbase + wj * 16 + r) * 1024 + q * 8;
  f32x4 acc = (f32x4){0.f, 0.f, 0.f, 0.f};
  uint4 fa;
  if (tid < 128) fa = *(const uint4*)(ap);
  uint4 fb0 = *(const uint4*)(Bp);          // k-step 0
  uint4 fb1 = *(const uint4*)(Bp + 32);     // k-step 1 (2-deep prefetch)
  for (int k0 = 0; k0 < 1024; k0 += 32) {
    if (tid < 128) *(uint4*)&As[arow][ascol] = fa;
    __syncthreads();
    union { uint4 u; short8 s; } bu; bu.u = fb0;
    if (k0 + 32 < 1024 && tid < 128) fa = *(const uint4*)(ap + k0 + 32);
    fb0 = fb1;
    if (k0 + 64 < 1024) fb1 = *(const uint4*)(Bp + k0 + 64);
    short8 a0 = *(const short8*)&As[wi * 16 + r][c0];
    acc = MFMA16(a0, bu.s, acc);
    __syncthreads();
  }
  int gcol = dbase + wj * 16 + r;
#pragma unroll
  for (int reg = 0; reg < 4; ++reg) {
    long grow = (long)vt * 1024 + n * 64 + mt * 32 + wi * 16 + q * 4 + reg;
    ctxb[grow * 512 + gcol] = f2bf(acc[reg]);
  }
}

// ================================================================ out (1024 blocks, 32x32) = tanh(P + ctx @ W_bot)
__global__ __launch_bounds__(256) void k_out(const unsigned short* __restrict__ ctxb,
                                             const unsigned short* __restrict__ WoutT,
                                             const float* __restrict__ P,
                                             float* __restrict__ out) {
  __shared__ __align__(16) unsigned short As[32][32];
  __shared__ __align__(16) unsigned short Bs[32][32];
  const int tid = threadIdx.x;
  const int mbase = (blockIdx.x >> 4) * 32, nbase = (blockIdx.x & 15) * 32;
  const int wave = tid >> 6, lane = tid & 63;
  const int wi = wave >> 1, wj = wave & 1;
  const int q = lane >> 4, r = lane & 15;
  const int c0 = ((q ^ (r & 3)) * 8);
  const int arow = (tid & 127) >> 2, akc = tid & 3;
  const int ascol = ((akc ^ (arow & 3)) * 8);
  const unsigned short* ap = ctxb + (long)(mbase + arow) * 512 + akc * 8;
  const unsigned short* bp = WoutT + (long)(nbase + arow) * 1024 + 512 + akc * 8;
  f32x4 acc;
  {
    int pcol = nbase + wj * 16 + r;
#pragma unroll
    for (int reg = 0; reg < 4; ++reg) {
      int prow = (mbase + wi * 16 + q * 4 + reg) & 1023;
      acc[reg] = P[(long)prow * 512 + pcol];
    }
  }
  uint4 fa, fb;
  if (tid < 128) fa = *(const uint4*)(ap);
  else           fb = *(const uint4*)(bp);
  for (int k0 = 0; k0 < 512; k0 += 32) {
    if (tid < 128) *(uint4*)&As[arow][ascol] = fa;
    else           *(uint4*)&Bs[arow][ascol] = fb;
    __syncthreads();
    int kn = k0 + 32;
    if (kn < 512) {
      if (tid < 128) fa = *(const uint4*)(ap + kn);
      else           fb = *(const uint4*)(bp + kn);
    }
    short8 a0 = *(const short8*)&As[wi * 16 + r][c0];
    short8 b0 = *(const short8*)&Bs[wj * 16 + r][c0];
    acc = MFMA16(a0, b0, acc);
    __syncthreads();
  }
  int gcol = nbase + wj * 16 + r;
#pragma unroll
  for (int reg = 0; reg < 4; ++reg) {
    int grow = mbase + wi * 16 + q * 4 + reg;
    float z = acc[reg];
    float rc = __builtin_amdgcn_rcpf(1.f + __builtin_amdgcn_exp2f(z * TWO_LOG2E));
    out[(long)grow * 512 + gcol] = fmaf(-2.f, rc, 1.f);
  }
}

// ================================================================ launch
extern "C" void kernel_launch(void* const* d_in, const int* in_sizes, int n_in,
                              void* d_out, int out_size, void* d_ws, size_t ws_size,
                              hipStream_t stream) {
  const float* input = (const float*)d_in[0];   // [16,64,512]
  const float* mb    = (const float*)d_in[1];   // [16,1024,512]
  const float* W_q   = (const float*)d_in[2];   // [512,64]
  const float* W_ctx = (const float*)d_in[3];   // [512,64]
  const float* v     = (const float*)d_in[4];   // [64]
  const float* W_out = (const float*)d_in[5];   // [1024,512]
  const float* b_out = (const float*)d_in[6];   // [512]
  float* out = (float*)d_out;                   // [2,16,64,512]
  float* ws = (float*)d_ws;

  float* uhT = ws;
  float* wqo = ws + 1048576;
  unsigned short* alpha_bf = (unsigned short*)(ws + 1114112);
  unsigned short* yal_bf   = (unsigned short*)(ws + 1638400);
  unsigned short* WctxT = (unsigned short*)(ws + 2162688);
  unsigned short* WqT   = (unsigned short*)(ws + 2179072);
  unsigned short* WoutT = (unsigned short*)(ws + 2195456);
  unsigned short* ctxb  = (unsigned short*)(ws + 2457600);
  float* P = ws + 2981888;
  unsigned short* mbT = (unsigned short*)(ws + 3506176);

  k_prep<<<144, 256, 0, stream>>>(W_ctx, W_q, W_out, WctxT, WqT, WoutT);
  k_gemm1<<<1056, 256, 0, stream>>>(mb, input, WctxT, WqT, WoutT, b_out, uhT, wqo, P, mbT);
  k_scores<<<1024, 256, 0, stream>>>(uhT, wqo, v, alpha_bf, yal_bf);
  k_ctx<<<1024, 256, 0, stream>>>(alpha_bf, yal_bf, mbT, ctxb);
  k_out<<<1024, 256, 0, stream>>>(ctxb, WoutT, P, out);
}